// Round 8
// baseline (697.952 us; speedup 1.0000x reference)
//
#include <hip/hip_runtime.h>
#include <hip/hip_cooperative_groups.h>
#include <hip/hip_bf16.h>
#include <math.h>

namespace cg = cooperative_groups;

#define L_SEQ 512
#define DM 768
#define DI 1536
#define DS 64
#define DC 4
#define DR 48
#define NXD 176  // DR + 2*DS
#define NC 8     // time chunks
#define TC 64    // steps per chunk

typedef __attribute__((ext_vector_type(8))) short short8;
typedef __attribute__((ext_vector_type(4))) float float4v;

// sizes (elements)
#define NWI (2 * DI * DM)     // 2359296
#define NWX (NXD * DI)        // 270336
#define NWDT (DI * DR)        // 73728
#define NWO (DM * DI)         // 1179648
#define NXZ (L_SEQ * 2 * DI)  // 1572864
#define NXDBL (L_SEQ * NXD)   // 90112
#define NXR (L_SEQ * DM)      // 393216

// P0 job partition (LN rows + 1024-elem cvt/zero chunks)
#define J_LN 512
#define J_WI (NWI / 1024)     // 2304
#define J_WX (NWX / 1024)     // 264
#define J_WDT (NWDT / 1024)   // 72
#define J_WO (NWO / 1024)     // 1152
#define J_ZXD (NXDBL / 1024)  // 88
#define NJOBS (J_LN + J_WI + J_WX + J_WDT + J_WO + J_ZXD)  // 4392

#define GRID_BLOCKS 512

struct Params {
  const float *x, *lnw, *lnb, *wi, *conv_w, *conv_b, *wx, *wdt, *dt_b, *A_log, *Dv, *wo;
  float *out;
  float *xz, *xconv, *xdbl, *dtb, *send, *dts, *sinit;
  short *h_bf, *wi_bf, *wx_bf, *wdt_bf, *wo_bf, *xc_bf, *y_bf;
};

// ---------------------------------------------------------------------------
// helpers
// ---------------------------------------------------------------------------
__device__ __forceinline__ float bp_add(float p, int addr) {
  return p + __int_as_float(__builtin_amdgcn_ds_bpermute(addr, __float_as_int(p)));
}
__device__ __forceinline__ float lane_read(float v, int t) {
  return __int_as_float(__builtin_amdgcn_readlane(__float_as_int(v), t));
}
__device__ __forceinline__ short f2bf(float v) {
  __hip_bfloat16 h = __float2bfloat16(v);
  return *reinterpret_cast<short*>(&h);
}
__device__ __forceinline__ short8 cvt8f(const float* p, bool valid) {
  float4 u = *(const float4*)(p);
  float4 v = *(const float4*)(p + 4);
  short8 r;
  r[0] = f2bf(u.x); r[1] = f2bf(u.y); r[2] = f2bf(u.z); r[3] = f2bf(u.w);
  r[4] = f2bf(v.x); r[5] = f2bf(v.y); r[6] = f2bf(v.z); r[7] = f2bf(v.w);
  if (!valid) r = (short8)0;
  return r;
}
__device__ __forceinline__ void atomic_addf(float* p, float v) {
  __hip_atomic_fetch_add(p, v, __ATOMIC_RELAXED, __HIP_MEMORY_SCOPE_AGENT);
}
__device__ __forceinline__ void cvt_blk(const float* __restrict__ s,
                                        short* __restrict__ d, int b) {
  int i = b * 1024 + threadIdx.x * 4;
  float4 v = *(const float4*)(s + i);
  short4 o; o.x = f2bf(v.x); o.y = f2bf(v.y); o.z = f2bf(v.z); o.w = f2bf(v.w);
  *(short4*)(d + i) = o;
}

// ---------------------------------------------------------------------------
// bf16-MFMA GEMM tile (verified fragment math, R4-R7):
// operand lane holds [r=lane&15][k=(lane>>4)*8+j]; C/D col=lane&15,
// row=(lane>>4)*4+reg. Block=4 waves; wave w owns the (w&1) 32m x (w>>1) 32n
// quadrant of a 64x64 tile; K-loop x2-unrolled, depth-2 prefetch.
// mode 0: plain store. mode 1: atomic add. mode 2: store res + acc.
// kchunk % 64 == 0 required.
// ---------------------------------------------------------------------------
__device__ __forceinline__ void gemm_tile(const short* A, int lda,
                                          const short* B, int ldb,
                                          float* C, int N,
                                          int kbeg, int kchunk,
                                          const float* res, int mode,
                                          int bx, int by, int lane, int w) {
  int fr = lane & 15, koff = (lane >> 4) * 8;
  int mbase = by * 64 + (w & 1) * 32;
  int nbase = bx * 64 + (w >> 1) * 32;
  int nr0 = nbase + fr;      if (nr0 > N - 1) nr0 = N - 1;
  int nr1 = nbase + 16 + fr; if (nr1 > N - 1) nr1 = N - 1;
  const short* pA0 = A + (size_t)(mbase + fr) * lda + koff + kbeg;
  const short* pA1 = pA0 + (size_t)16 * lda;
  const short* pB0 = B + (size_t)nr0 * ldb + koff + kbeg;
  const short* pB1 = B + (size_t)nr1 * ldb + koff + kbeg;
  float4v acc00 = (float4v){0.f,0.f,0.f,0.f}, acc01 = acc00;
  float4v acc10 = acc00, acc11 = acc00;
  short8 a0A = *(const short8*)(pA0);      short8 a1A = *(const short8*)(pA1);
  short8 b0A = *(const short8*)(pB0);      short8 b1A = *(const short8*)(pB1);
  short8 a0B = *(const short8*)(pA0 + 32); short8 a1B = *(const short8*)(pA1 + 32);
  short8 b0B = *(const short8*)(pB0 + 32); short8 b1B = *(const short8*)(pB1 + 32);
  for (int k0 = 0; k0 < kchunk; k0 += 64) {
    short8 ca0 = a0A, ca1 = a1A, cb0 = b0A, cb1 = b1A;
    short8 da0 = a0B, da1 = a1B, db0 = b0B, db1 = b1B;
    int nA = k0 + 64; if (nA >= kchunk) nA = 0;
    int nB = k0 + 96; if (nB >= kchunk) nB = 32;
    a0A = *(const short8*)(pA0 + nA); a1A = *(const short8*)(pA1 + nA);
    b0A = *(const short8*)(pB0 + nA); b1A = *(const short8*)(pB1 + nA);
    a0B = *(const short8*)(pA0 + nB); a1B = *(const short8*)(pA1 + nB);
    b0B = *(const short8*)(pB0 + nB); b1B = *(const short8*)(pB1 + nB);
    acc00 = __builtin_amdgcn_mfma_f32_16x16x32_bf16(ca0, cb0, acc00, 0, 0, 0);
    acc01 = __builtin_amdgcn_mfma_f32_16x16x32_bf16(ca0, cb1, acc01, 0, 0, 0);
    acc10 = __builtin_amdgcn_mfma_f32_16x16x32_bf16(ca1, cb0, acc10, 0, 0, 0);
    acc11 = __builtin_amdgcn_mfma_f32_16x16x32_bf16(ca1, cb1, acc11, 0, 0, 0);
    acc00 = __builtin_amdgcn_mfma_f32_16x16x32_bf16(da0, db0, acc00, 0, 0, 0);
    acc01 = __builtin_amdgcn_mfma_f32_16x16x32_bf16(da0, db1, acc01, 0, 0, 0);
    acc10 = __builtin_amdgcn_mfma_f32_16x16x32_bf16(da1, db0, acc10, 0, 0, 0);
    acc11 = __builtin_amdgcn_mfma_f32_16x16x32_bf16(da1, db1, acc11, 0, 0, 0);
  }
  int col0 = nbase + fr, col1 = nbase + 16 + fr;
  int rb = mbase + (lane >> 4) * 4;
#pragma unroll
  for (int r = 0; r < 4; ++r) {
    size_t o00 = (size_t)(rb + r) * N;
    size_t o10 = (size_t)(rb + 16 + r) * N;
    if (col0 < N) {
      if (mode == 1) {
        atomic_addf(&C[o00 + col0], acc00[r]);
        atomic_addf(&C[o10 + col0], acc10[r]);
      } else {
        float v0 = acc00[r], v1 = acc10[r];
        if (mode == 2) { v0 += res[o00 + col0]; v1 += res[o10 + col0]; }
        C[o00 + col0] = v0; C[o10 + col0] = v1;
      }
    }
    if (col1 < N) {
      if (mode == 1) {
        atomic_addf(&C[o00 + col1], acc01[r]);
        atomic_addf(&C[o10 + col1], acc11[r]);
      } else {
        float v0 = acc01[r], v1 = acc11[r];
        if (mode == 2) { v0 += res[o00 + col1]; v1 += res[o10 + col1]; }
        C[o00 + col1] = v0; C[o10 + col1] = v1;
      }
    }
  }
}

// dt_proj tile: softplus(xdbl[:, :48] . Wdt^T + bias), K=48 padded to 64
__device__ __forceinline__ void dtp_tile(const float* Axd, const short* Bw,
                                         float* dt, const float* bias,
                                         int bx, int by, int lane, int w) {
  int fr = lane & 15, koff = (lane >> 4) * 8;
  int mbase = by * 64 + (w & 1) * 32;
  int nbase = bx * 64 + (w >> 1) * 32;
  const float* pA0 = Axd + (size_t)(mbase + fr) * NXD;
  const float* pA1 = pA0 + (size_t)16 * NXD;
  const short* pB0 = Bw + (size_t)(nbase + fr) * DR;
  const short* pB1 = Bw + (size_t)(nbase + 16 + fr) * DR;
  float4v acc00 = (float4v){0.f,0.f,0.f,0.f}, acc01 = acc00;
  float4v acc10 = acc00, acc11 = acc00;
#pragma unroll
  for (int k0 = 0; k0 < 64; k0 += 32) {
    bool valid = (k0 + koff) < DR;
    int off = valid ? k0 + koff : 0;
    short8 a0 = cvt8f(pA0 + off, valid);
    short8 a1 = cvt8f(pA1 + off, valid);
    short8 b0 = *(const short8*)(pB0 + off);
    short8 b1 = *(const short8*)(pB1 + off);
    if (!valid) { b0 = (short8)0; b1 = (short8)0; }
    acc00 = __builtin_amdgcn_mfma_f32_16x16x32_bf16(a0, b0, acc00, 0, 0, 0);
    acc01 = __builtin_amdgcn_mfma_f32_16x16x32_bf16(a0, b1, acc01, 0, 0, 0);
    acc10 = __builtin_amdgcn_mfma_f32_16x16x32_bf16(a1, b0, acc10, 0, 0, 0);
    acc11 = __builtin_amdgcn_mfma_f32_16x16x32_bf16(a1, b1, acc11, 0, 0, 0);
  }
  int col0 = nbase + fr, col1 = nbase + 16 + fr;
  float bi0 = bias[col0], bi1 = bias[col1];
  int rb = mbase + (lane >> 4) * 4;
#pragma unroll
  for (int r = 0; r < 4; ++r) {
    float v0 = acc00[r] + bi0, v1 = acc01[r] + bi1;
    float v2 = acc10[r] + bi0, v3 = acc11[r] + bi1;
    v0 = (v0 > 20.f) ? v0 : log1pf(__expf(v0));
    v1 = (v1 > 20.f) ? v1 : log1pf(__expf(v1));
    v2 = (v2 > 20.f) ? v2 : log1pf(__expf(v2));
    v3 = (v3 > 20.f) ? v3 : log1pf(__expf(v3));
    dt[(size_t)(rb + r) * DI + col0] = v0;
    dt[(size_t)(rb + r) * DI + col1] = v1;
    dt[(size_t)(rb + 16 + r) * DI + col0] = v2;
    dt[(size_t)(rb + 16 + r) * DI + col1] = v3;
  }
}

// ---------------------------------------------------------------------------
// The cooperative mega-kernel: 9 phases, 8 grid syncs, 1 dispatch.
// ---------------------------------------------------------------------------
__global__ __launch_bounds__(256, 2) void mamba_mega(Params p) {
  cg::grid_group grid = cg::this_grid();
  const int tid = threadIdx.x;
  const int lane = tid & 63, wid = tid >> 6;
  const int gb = blockIdx.x;
  __shared__ float Pb[4][16][66];
  __shared__ float ls[4], ls2[4];

  // ---- P0: LN + weight cvts + zero xdbl ----
  for (int job = gb; job < NJOBS; job += GRID_BLOCKS) {
    if (job < J_LN) {
      int l = job;
      const float* xr = p.x + l * DM;
      float s = 0.f, s2 = 0.f;
      for (int i = tid; i < DM; i += 256) { float t = xr[i]; s += t; s2 += t * t; }
#pragma unroll
      for (int off = 32; off; off >>= 1) { s += __shfl_xor(s, off); s2 += __shfl_xor(s2, off); }
      if (lane == 0) { ls[wid] = s; ls2[wid] = s2; }
      __syncthreads();
      s = ls[0] + ls[1] + ls[2] + ls[3];
      s2 = ls2[0] + ls2[1] + ls2[2] + ls2[3];
      __syncthreads();
      float mean = s * (1.f / DM);
      float var = s2 * (1.f / DM) - mean * mean;
      float rstd = rsqrtf(var + 1e-5f);
      for (int i = tid; i < DM; i += 256)
        p.h_bf[l * DM + i] = f2bf((xr[i] - mean) * rstd * p.lnw[i] + p.lnb[i]);
      continue;
    }
    int b = job - J_LN;
    if (b < J_WI) { cvt_blk(p.wi, p.wi_bf, b); continue; }
    b -= J_WI;
    if (b < J_WX) { cvt_blk(p.wx, p.wx_bf, b); continue; }
    b -= J_WX;
    if (b < J_WDT) { cvt_blk(p.wdt, p.wdt_bf, b); continue; }
    b -= J_WDT;
    if (b < J_WO) { cvt_blk(p.wo, p.wo_bf, b); continue; }
    b -= J_WO;
    { int i = b * 1024 + tid * 4; *(float4*)(p.xdbl + i) = make_float4(0.f, 0.f, 0.f, 0.f); }
  }
  grid.sync();

  // ---- P1: in_proj xz = h . Wi^T  (48x8 = 384 tiles) ----
  if (gb < 384)
    gemm_tile(p.h_bf, DM, p.wi_bf, DM, p.xz, 2 * DI, 0, DM, nullptr, 0,
              gb % 48, gb / 48, lane, wid);
  grid.sync();

  // ---- P2: causal depthwise conv + SiLU (f32 + bf16 stores) ----
  for (int blk = gb; blk < (L_SEQ * DI) / 256; blk += GRID_BLOCKS) {
    int idx = blk * 256 + tid;
    int l = idx / DI, d = idx - l * DI;
    float acc = p.conv_b[d];
#pragma unroll
    for (int j = 0; j < DC; ++j) {
      int ll = l - (DC - 1) + j;
      if (ll >= 0) acc = fmaf(p.xz[(size_t)ll * (2 * DI) + d], p.conv_w[d * DC + j], acc);
    }
    float sig = 1.f / (1.f + __expf(-acc));
    float v = acc * sig;
    p.xconv[idx] = v;
    p.xc_bf[idx] = f2bf(v);
  }
  grid.sync();

  // ---- P3: x_proj xdbl += xconv . Wx^T  (3x8 tiles x 8 ksplit, atomics) ----
  if (gb < 192) {
    int bx = gb % 3, by = (gb / 3) % 8, bz = gb / 24;
    gemm_tile(p.xc_bf, DI, p.wx_bf, DI, p.xdbl, NXD, bz * 192, 192, nullptr, 1,
              bx, by, lane, wid);
  }
  grid.sync();

  // ---- P4: dt_proj + softplus (24x8 tiles) ----
  if (gb < 192)
    dtp_tile(p.xdbl, p.wdt_bf, p.dtb, p.dt_b, gb % 24, gb / 24, lane, wid);
  grid.sync();

  // ---- P5: scan pass 1 (chunks 0..NC-2) ----
  for (int g = gb; g < ((NC - 1) * DI) / 4; g += GRID_BLOCKS) {
    int pair = g * 4 + wid;
    int c = __builtin_amdgcn_readfirstlane(pair / DI);
    int d = __builtin_amdgcn_readfirstlane(pair - (pair / DI) * DI);
    float A = -__expf(p.A_log[(size_t)d * DS + lane]);
    int l0 = c * TC;
    float dtv = p.dtb[(size_t)(l0 + lane) * DI + d];
    float xv  = p.xconv[(size_t)(l0 + lane) * DI + d];
    const float* pB = p.xdbl + (size_t)l0 * NXD + DR + lane;
    float s = 0.f;
#pragma unroll 8
    for (int t = 0; t < TC; ++t) {
      float dt_c = lane_read(dtv, t);
      float x_c  = lane_read(xv, t);
      float B_c  = pB[(size_t)t * NXD];
      float dA = __expf(dt_c * A);
      s = fmaf(dA, s, dt_c * x_c * B_c);
    }
    float dsum = dtv;
    dsum = bp_add(dsum, (lane ^ 1) << 2);  dsum = bp_add(dsum, (lane ^ 2) << 2);
    dsum = bp_add(dsum, (lane ^ 4) << 2);  dsum = bp_add(dsum, (lane ^ 8) << 2);
    dsum = bp_add(dsum, (lane ^ 16) << 2); dsum = bp_add(dsum, (lane ^ 32) << 2);
    p.send[((size_t)c * DI + d) * DS + lane] = s;
    if (lane == 0) p.dts[c * DI + d] = dsum;
  }
  grid.sync();

  // ---- P6: scan pass 2 (prefix over chunks) ----
  if (gb < DI / 4) {
    int d = __builtin_amdgcn_readfirstlane(gb * 4 + wid);
    float A = -__expf(p.A_log[(size_t)d * DS + lane]);
    float s = 0.f;
    for (int c = 1; c < NC; ++c) {
      float P = __expf(A * p.dts[(c - 1) * DI + d]);
      s = fmaf(P, s, p.send[((size_t)(c - 1) * DI + d) * DS + lane]);
      p.sinit[((size_t)c * DI + d) * DS + lane] = s;
    }
  }
  grid.sync();

  // ---- P7: scan pass 3 (true init; LDS-batched n-reduction; bf16 y) ----
  for (int g = gb; g < (NC * DI) / 4; g += GRID_BLOCKS) {
    int pair = g * 4 + wid;
    int c = __builtin_amdgcn_readfirstlane(pair / DI);
    int d = __builtin_amdgcn_readfirstlane(pair - (pair / DI) * DI);
    float A = -__expf(p.A_log[(size_t)d * DS + lane]);
    float Dd = p.Dv[d];
    int l0 = c * TC;
    float dtv = p.dtb[(size_t)(l0 + lane) * DI + d];
    float xv  = p.xconv[(size_t)(l0 + lane) * DI + d];
    float zv  = p.xz[(size_t)(l0 + lane) * (2 * DI) + DI + d];
    float s = (c == 0) ? 0.f : p.sinit[((size_t)c * DI + d) * DS + lane];
    const float* pB = p.xdbl + (size_t)l0 * NXD + DR + lane;
    float yv = 0.f;
#pragma unroll
    for (int sb = 0; sb < 4; ++sb) {
      float P[16];
#pragma unroll
      for (int j = 0; j < 16; ++j) {
        int t = sb * 16 + j;
        float dt_c = lane_read(dtv, t);
        float x_c  = lane_read(xv, t);
        float B_c  = pB[(size_t)t * NXD];
        float C_c  = pB[(size_t)t * NXD + DS];
        float dA = __expf(dt_c * A);
        s = fmaf(dA, s, dt_c * x_c * B_c);
        P[j] = s * C_c;
      }
#pragma unroll
      for (int j = 0; j < 16; ++j) Pb[wid][j][lane] = P[j];
      int t4 = lane >> 2, q = lane & 3;
      const float* row = &Pb[wid][t4][q * 16];
      float part = 0.f;
#pragma unroll
      for (int k = 0; k < 8; ++k) {
        float2 v2 = *(const float2*)(row + 2 * k);
        part += v2.x + v2.y;
      }
      part = bp_add(part, (lane ^ 1) << 2);
      part = bp_add(part, (lane ^ 2) << 2);
      float got = __int_as_float(
          __builtin_amdgcn_ds_bpermute((lane & 15) << 4, __float_as_int(part)));
      yv = ((lane >> 4) == sb) ? got : yv;
    }
    float sig = 1.f / (1.f + __expf(-zv));
    p.y_bf[(size_t)(l0 + lane) * DI + d] = f2bf((yv + xv * Dd) * (zv * sig));
  }
  grid.sync();

  // ---- P8: out_proj + residual (12x8 = 96 tiles) ----
  if (gb < 96)
    gemm_tile(p.y_bf, DI, p.wo_bf, DI, p.out, DM, 0, DI, p.x, 2,
              gb % 12, gb / 12, lane, wid);
}

// ---------------------------------------------------------------------------
// Launcher: ONE cooperative dispatch.
// ---------------------------------------------------------------------------
extern "C" void kernel_launch(void* const* d_in, const int* in_sizes, int n_in,
                              void* d_out, int out_size, void* d_ws, size_t ws_size,
                              hipStream_t stream) {
  Params p;
  p.x      = (const float*)d_in[0];
  p.lnw    = (const float*)d_in[1];
  p.lnb    = (const float*)d_in[2];
  p.wi     = (const float*)d_in[3];
  p.conv_w = (const float*)d_in[4];
  p.conv_b = (const float*)d_in[5];
  p.wx     = (const float*)d_in[6];
  p.wdt    = (const float*)d_in[7];
  p.dt_b   = (const float*)d_in[8];
  p.A_log  = (const float*)d_in[9];
  p.Dv     = (const float*)d_in[10];
  p.wo     = (const float*)d_in[11];
  p.out    = (float*)d_out;

  float* ws = (float*)d_ws;
  p.xz    = ws;                  // 1572864
  p.xconv = p.xz + NXZ;          // 786432
  p.xdbl  = p.xconv + L_SEQ*DI;  // 90112
  p.dtb   = p.xdbl + NXDBL;      // 786432
  p.send  = p.dtb + L_SEQ*DI;    // 688128
  p.dts   = p.send + 688128;     // 10752
  p.sinit = p.dts + 10752;       // 786432
  float* fend = p.sinit + 786432;
  p.h_bf   = (short*)fend;       // 393216
  p.wi_bf  = p.h_bf + NXR;       // 2359296
  p.wx_bf  = p.wi_bf + NWI;      // 270336
  p.wdt_bf = p.wx_bf + NWX;      // 73728
  p.wo_bf  = p.wdt_bf + NWDT;    // 1179648
  p.xc_bf  = p.wo_bf + NWO;      // 786432
  p.y_bf   = p.xc_bf + L_SEQ*DI; // 786432

  void* args[] = { (void*)&p };
  hipLaunchCooperativeKernel((const void*)mamba_mega, dim3(GRID_BLOCKS),
                             dim3(256), args, 0, stream);
}

// Round 9
// 204.969 us; speedup vs baseline: 3.4052x; 3.4052x over previous
//
#include <hip/hip_runtime.h>
#include <hip/hip_bf16.h>
#include <math.h>

#define L_SEQ 512
#define DM 768
#define DI 1536
#define DS 64
#define DC 4
#define DR 48
#define NBC 128          // B/C output columns (2*DS)
#define NP2 (NBC + DI)   // 1664: proj2 output width (B/C | dt)
#define NC 8             // time chunks
#define TC 64            // steps per chunk

typedef __attribute__((ext_vector_type(8))) short short8;
typedef __attribute__((ext_vector_type(4))) float float4v;

// prep job partition (1024-elem cvt jobs + LN rows + Weff tiles)
#define J_LN 512
#define J_WI (2 * DI * DM / 1024)   // 2304
#define J_WBC (NBC * DI / 1024)     // 192
#define J_WO (DM * DI / 1024)       // 1152
#define J_WEFF ((DI / 64) * (DI / 64))  // 576
#define PREP_GRID (J_LN + J_WI + J_WBC + J_WO + J_WEFF)  // 4736

// ---------------------------------------------------------------------------
// helpers
// ---------------------------------------------------------------------------
__device__ __forceinline__ float bp_add(float p, int addr) {
  return p + __int_as_float(__builtin_amdgcn_ds_bpermute(addr, __float_as_int(p)));
}
__device__ __forceinline__ float lane_read(float v, int t) {
  return __int_as_float(__builtin_amdgcn_readlane(__float_as_int(v), t));
}
__device__ __forceinline__ short f2bf(float v) {
  __hip_bfloat16 h = __float2bfloat16(v);
  return *reinterpret_cast<short*>(&h);
}
__device__ __forceinline__ short8 cvt8f(const float* p, bool valid) {
  float4 u = *(const float4*)(p);
  float4 v = *(const float4*)(p + 4);
  short8 r;
  r[0] = f2bf(u.x); r[1] = f2bf(u.y); r[2] = f2bf(u.z); r[3] = f2bf(u.w);
  r[4] = f2bf(v.x); r[5] = f2bf(v.y); r[6] = f2bf(v.z); r[7] = f2bf(v.w);
  if (!valid) r = (short8)0;
  return r;
}
__device__ __forceinline__ void cvt_blk(const float* __restrict__ s,
                                        short* __restrict__ d, int b) {
  int i = b * 1024 + threadIdx.x * 4;
  float4 v = *(const float4*)(s + i);
  short4 o; o.x = f2bf(v.x); o.y = f2bf(v.y); o.z = f2bf(v.z); o.w = f2bf(v.w);
  *(short4*)(d + i) = o;
}

// ---------------------------------------------------------------------------
// 32x32-tile GEMM core with 4-wave intra-block K-split + LDS reduce.
// C[M,N] = A[M,K].B[N,K]^T, both bf16 row-major (lda/ldb row strides).
// Wave w computes the full 32x32 tile over K-slice [w*K/4,(w+1)*K/4),
// depth-2 prefetch (x2-unrolled loop; requires (K/4) % 64 == 0... K/4 is
// 192 or 384 here -> loop steps of 64 with clamped prefetch addresses).
// After LDS reduce, wave w holds the 16x16 quadrant (qi=w&1, qj=w>>1):
// v[r] -> C[row+r][col], row/col returned. Fragment math verified R4-R7.
// ---------------------------------------------------------------------------
__device__ __forceinline__ float4v gemm32_core(
    const short* __restrict__ A, int lda, const short* __restrict__ B, int ldb,
    int K, int bx, int by, int lane, int w, float4v* red,
    int* prow, int* pcol) {
  int ks = K >> 2;
  int kbeg = w * ks;
  int fr = lane & 15, koff = (lane >> 4) * 8;
  int m0 = by * 32, n0 = bx * 32;
  const short* pA0 = A + (size_t)(m0 + fr) * lda + koff + kbeg;
  const short* pA1 = pA0 + (size_t)16 * lda;
  const short* pB0 = B + (size_t)(n0 + fr) * ldb + koff + kbeg;
  const short* pB1 = pB0 + (size_t)16 * ldb;
  float4v acc00 = (float4v){0.f,0.f,0.f,0.f}, acc01 = acc00;
  float4v acc10 = acc00, acc11 = acc00;
  short8 a0A = *(const short8*)(pA0);      short8 a1A = *(const short8*)(pA1);
  short8 b0A = *(const short8*)(pB0);      short8 b1A = *(const short8*)(pB1);
  short8 a0B = *(const short8*)(pA0 + 32); short8 a1B = *(const short8*)(pA1 + 32);
  short8 b0B = *(const short8*)(pB0 + 32); short8 b1B = *(const short8*)(pB1 + 32);
  for (int k0 = 0; k0 < ks; k0 += 64) {
    short8 ca0 = a0A, ca1 = a1A, cb0 = b0A, cb1 = b1A;
    short8 da0 = a0B, da1 = a1B, db0 = b0B, db1 = b1B;
    int nA = k0 + 64; if (nA >= ks) nA = 0;
    int nB = k0 + 96; if (nB >= ks) nB = 32;
    a0A = *(const short8*)(pA0 + nA); a1A = *(const short8*)(pA1 + nA);
    b0A = *(const short8*)(pB0 + nA); b1A = *(const short8*)(pB1 + nA);
    a0B = *(const short8*)(pA0 + nB); a1B = *(const short8*)(pA1 + nB);
    b0B = *(const short8*)(pB0 + nB); b1B = *(const short8*)(pB1 + nB);
    acc00 = __builtin_amdgcn_mfma_f32_16x16x32_bf16(ca0, cb0, acc00, 0, 0, 0);
    acc01 = __builtin_amdgcn_mfma_f32_16x16x32_bf16(ca0, cb1, acc01, 0, 0, 0);
    acc10 = __builtin_amdgcn_mfma_f32_16x16x32_bf16(ca1, cb0, acc10, 0, 0, 0);
    acc11 = __builtin_amdgcn_mfma_f32_16x16x32_bf16(ca1, cb1, acc11, 0, 0, 0);
    acc00 = __builtin_amdgcn_mfma_f32_16x16x32_bf16(da0, db0, acc00, 0, 0, 0);
    acc01 = __builtin_amdgcn_mfma_f32_16x16x32_bf16(da0, db1, acc01, 0, 0, 0);
    acc10 = __builtin_amdgcn_mfma_f32_16x16x32_bf16(da1, db0, acc10, 0, 0, 0);
    acc11 = __builtin_amdgcn_mfma_f32_16x16x32_bf16(da1, db1, acc11, 0, 0, 0);
  }
  red[(w * 4 + 0) * 64 + lane] = acc00;
  red[(w * 4 + 1) * 64 + lane] = acc01;
  red[(w * 4 + 2) * 64 + lane] = acc10;
  red[(w * 4 + 3) * 64 + lane] = acc11;
  __syncthreads();
  float4v v = red[(0 * 4 + w) * 64 + lane];
  v = v + red[(1 * 4 + w) * 64 + lane];
  v = v + red[(2 * 4 + w) * 64 + lane];
  v = v + red[(3 * 4 + w) * 64 + lane];
  int qi = w & 1, qj = w >> 1;
  *prow = m0 + qi * 16 + (lane >> 4) * 4;
  *pcol = n0 + qj * 16 + (lane & 15);
  return v;
}

// ---------------------------------------------------------------------------
// prep: LN + cvt(Wi) + cvt(Wx B/C rows -> Wcomb[0..127]) + cvt(Wo)
//       + Weff GEMM tiles (Wcomb[128..1663] = Wdt . Wx_dt, K=48 pad 64).
// ---------------------------------------------------------------------------
__global__ __launch_bounds__(256) void prep(
    const float* __restrict__ x, const float* __restrict__ lnw,
    const float* __restrict__ lnb, short* __restrict__ h,
    const float* __restrict__ wi, short* __restrict__ wib,
    const float* __restrict__ wx, const float* __restrict__ wdt,
    short* __restrict__ wcomb, const float* __restrict__ wo,
    short* __restrict__ wob) {
  __shared__ float ls[4], ls2[4];
  int b = blockIdx.x;
  int tid = threadIdx.x, lane = tid & 63, w = tid >> 6;
  if (b < J_LN) {  // LayerNorm row b -> bf16 h
    int l = b;
    const float* xr = x + l * DM;
    float s = 0.f, s2 = 0.f;
    for (int i = tid; i < DM; i += 256) { float t = xr[i]; s += t; s2 += t * t; }
#pragma unroll
    for (int off = 32; off; off >>= 1) { s += __shfl_xor(s, off); s2 += __shfl_xor(s2, off); }
    if (lane == 0) { ls[w] = s; ls2[w] = s2; }
    __syncthreads();
    s = ls[0] + ls[1] + ls[2] + ls[3];
    s2 = ls2[0] + ls2[1] + ls2[2] + ls2[3];
    float mean = s * (1.f / DM);
    float var = s2 * (1.f / DM) - mean * mean;
    float rstd = rsqrtf(var + 1e-5f);
    for (int i = tid; i < DM; i += 256)
      h[l * DM + i] = f2bf((xr[i] - mean) * rstd * lnw[i] + lnb[i]);
    return;
  }
  b -= J_LN;
  if (b < J_WI) { cvt_blk(wi, wib, b); return; }
  b -= J_WI;
  if (b < J_WBC) { cvt_blk(wx + DR * DI, wcomb, b); return; }  // B/C rows
  b -= J_WBC;
  if (b < J_WO) { cvt_blk(wo, wob, b); return; }
  b -= J_WO;
  // Weff tile: Wcomb[128+m][n] = sum_r wdt[m][r] * wx[r][n]  (r < 48)
  {
    int tm = b / (DI / 64), tn = b % (DI / 64);
    int qi = w & 1, qj = w >> 1;
    int m0 = tm * 64 + qi * 32, n0 = tn * 64 + qj * 32;
    int fr = lane & 15, koff = (lane >> 4) * 8;
    const float* pA0 = wdt + (size_t)(m0 + fr) * DR;
    const float* pA1 = pA0 + (size_t)16 * DR;
    float4v a00 = (float4v){0.f,0.f,0.f,0.f}, a01 = a00, a10 = a00, a11 = a00;
#pragma unroll
    for (int k0 = 0; k0 < 64; k0 += 32) {
      bool valid = (k0 + koff) < DR;   // 8-groups are fully valid or invalid
      int off = valid ? k0 + koff : 0;
      short8 fa0 = cvt8f(pA0 + off, valid);
      short8 fa1 = cvt8f(pA1 + off, valid);
      short8 fb0, fb1;
#pragma unroll
      for (int j = 0; j < 8; ++j) {
        int r = k0 + koff + j;
        fb0[j] = valid ? f2bf(wx[(size_t)r * DI + n0 + fr]) : (short)0;
        fb1[j] = valid ? f2bf(wx[(size_t)r * DI + n0 + 16 + fr]) : (short)0;
      }
      a00 = __builtin_amdgcn_mfma_f32_16x16x32_bf16(fa0, fb0, a00, 0, 0, 0);
      a01 = __builtin_amdgcn_mfma_f32_16x16x32_bf16(fa0, fb1, a01, 0, 0, 0);
      a10 = __builtin_amdgcn_mfma_f32_16x16x32_bf16(fa1, fb0, a10, 0, 0, 0);
      a11 = __builtin_amdgcn_mfma_f32_16x16x32_bf16(fa1, fb1, a11, 0, 0, 0);
    }
    int rb = (lane >> 4) * 4, cb = lane & 15;
#pragma unroll
    for (int r = 0; r < 4; ++r) {
      wcomb[(size_t)(NBC + m0 + rb + r) * DI + n0 + cb]      = f2bf(a00[r]);
      wcomb[(size_t)(NBC + m0 + rb + r) * DI + n0 + 16 + cb] = f2bf(a01[r]);
      wcomb[(size_t)(NBC + m0 + 16 + rb + r) * DI + n0 + cb]      = f2bf(a10[r]);
      wcomb[(size_t)(NBC + m0 + 16 + rb + r) * DI + n0 + 16 + cb] = f2bf(a11[r]);
    }
  }
}

// ---------------------------------------------------------------------------
// in_proj: xz[512, 3072] = h . Wi^T   (grid 96 x 16)
// ---------------------------------------------------------------------------
__global__ __launch_bounds__(256) void k_inproj(const short* __restrict__ h,
                                                const short* __restrict__ wi,
                                                float* __restrict__ xz) {
  __shared__ float4v red[16 * 64];
  int lane = threadIdx.x & 63, w = threadIdx.x >> 6;
  int row, col;
  float4v v = gemm32_core(h, DM, wi, DM, DM, blockIdx.x, blockIdx.y,
                          lane, w, red, &row, &col);
#pragma unroll
  for (int r = 0; r < 4; ++r)
    xz[(size_t)(row + r) * (2 * DI) + col] = v[r];
}

// ---------------------------------------------------------------------------
// conv + SiLU (f32 + bf16 stores)
// ---------------------------------------------------------------------------
__global__ __launch_bounds__(256) void conv_silu_kernel(const float* __restrict__ xz,
                                                        const float* __restrict__ cw,
                                                        const float* __restrict__ cb,
                                                        float* __restrict__ xc,
                                                        short* __restrict__ xcb) {
  int idx = blockIdx.x * 256 + threadIdx.x;
  int l = idx / DI, d = idx - l * DI;
  float acc = cb[d];
#pragma unroll
  for (int j = 0; j < DC; ++j) {
    int ll = l - (DC - 1) + j;
    if (ll >= 0) acc = fmaf(xz[(size_t)ll * (2 * DI) + d], cw[d * DC + j], acc);
  }
  float sig = 1.f / (1.f + __expf(-acc));
  float v = acc * sig;
  xc[idx] = v;
  xcb[idx] = f2bf(v);
}

// ---------------------------------------------------------------------------
// proj2: [B/C | dt] = xconv . Wcomb^T   (grid 52 x 16, N=1664, K=1536)
// cols < 128 -> xdblBC f32; cols >= 128 -> softplus(v + bias) -> dtb.
// ---------------------------------------------------------------------------
__global__ __launch_bounds__(256) void k_proj2(const short* __restrict__ xc,
                                               const short* __restrict__ wcomb,
                                               float* __restrict__ xdblBC,
                                               float* __restrict__ dtb,
                                               const float* __restrict__ bias) {
  __shared__ float4v red[16 * 64];
  int lane = threadIdx.x & 63, w = threadIdx.x >> 6;
  int row, col;
  float4v v = gemm32_core(xc, DI, wcomb, DI, DI, blockIdx.x, blockIdx.y,
                          lane, w, red, &row, &col);
  if (col < NBC) {
#pragma unroll
    for (int r = 0; r < 4; ++r)
      xdblBC[(size_t)(row + r) * NBC + col] = v[r];
  } else {
    int d = col - NBC;
    float bi = bias[d];
#pragma unroll
    for (int r = 0; r < 4; ++r) {
      float t = v[r] + bi;
      t = (t > 20.f) ? t : log1pf(__expf(t));
      dtb[(size_t)(row + r) * DI + d] = t;
    }
  }
}

// ---------------------------------------------------------------------------
// Scan pass 1 (chunks 0..NC-2): local recurrence from 0; emit end state + sum(dt)
// ---------------------------------------------------------------------------
__global__ __launch_bounds__(256) void scan_p1(const float* __restrict__ dt,
                                               const float* __restrict__ xc,
                                               const float* __restrict__ xdblBC,
                                               const float* __restrict__ A_log,
                                               float* __restrict__ send,
                                               float* __restrict__ dts) {
  int lane = threadIdx.x & 63;
  int wid = threadIdx.x >> 6;
  int pair = blockIdx.x * 4 + wid;
  int c = __builtin_amdgcn_readfirstlane(pair / DI);
  int d = __builtin_amdgcn_readfirstlane(pair - (pair / DI) * DI);
  float A = -__expf(A_log[(size_t)d * DS + lane]);
  int l0 = c * TC;
  float dtv = dt[(size_t)(l0 + lane) * DI + d];
  float xv  = xc[(size_t)(l0 + lane) * DI + d];
  const float* pB = xdblBC + (size_t)l0 * NBC + lane;
  float s = 0.f;
#pragma unroll 8
  for (int t = 0; t < TC; ++t) {
    float dt_c = lane_read(dtv, t);
    float x_c  = lane_read(xv, t);
    float B_c  = pB[(size_t)t * NBC];
    float dA = __expf(dt_c * A);
    s = fmaf(dA, s, dt_c * x_c * B_c);
  }
  float dsum = dtv;
  dsum = bp_add(dsum, (lane ^ 1) << 2);  dsum = bp_add(dsum, (lane ^ 2) << 2);
  dsum = bp_add(dsum, (lane ^ 4) << 2);  dsum = bp_add(dsum, (lane ^ 8) << 2);
  dsum = bp_add(dsum, (lane ^ 16) << 2); dsum = bp_add(dsum, (lane ^ 32) << 2);
  send[((size_t)c * DI + d) * DS + lane] = s;
  if (lane == 0) dts[c * DI + d] = dsum;
}

// ---------------------------------------------------------------------------
// Scan pass 3: inline chunk-prefix (<=7 steps) replaces pass 2; then the
// recurrence with LDS-batched n-reduction; bf16 y out.
// ---------------------------------------------------------------------------
__global__ __launch_bounds__(256) void scan_p3(const float* __restrict__ dt,
                                               const float* __restrict__ xc,
                                               const float* __restrict__ xdblBC,
                                               const float* __restrict__ A_log,
                                               const float* __restrict__ Dv,
                                               const float* __restrict__ xz,
                                               const float* __restrict__ send,
                                               const float* __restrict__ dts,
                                               short* __restrict__ y) {
  __shared__ float Pb[4][16][66];
  int lane = threadIdx.x & 63;
  int wid = threadIdx.x >> 6;
  int pair = blockIdx.x * 4 + wid;
  int c = __builtin_amdgcn_readfirstlane(pair / DI);
  int d = __builtin_amdgcn_readfirstlane(pair - (pair / DI) * DI);
  float A = -__expf(A_log[(size_t)d * DS + lane]);
  float Dd = Dv[d];
  int l0 = c * TC;
  float dtv = dt[(size_t)(l0 + lane) * DI + d];
  float xv  = xc[(size_t)(l0 + lane) * DI + d];
  float zv  = xz[(size_t)(l0 + lane) * (2 * DI) + DI + d];
  // inline prefix over previous chunks
  float s = 0.f;
  for (int cc = 0; cc < c; ++cc) {
    float P = __expf(A * dts[cc * DI + d]);
    s = fmaf(P, s, send[((size_t)cc * DI + d) * DS + lane]);
  }
  const float* pB = xdblBC + (size_t)l0 * NBC + lane;
  float yv = 0.f;
#pragma unroll
  for (int sb = 0; sb < 4; ++sb) {
    float P[16];
#pragma unroll
    for (int j = 0; j < 16; ++j) {
      int t = sb * 16 + j;
      float dt_c = lane_read(dtv, t);
      float x_c  = lane_read(xv, t);
      float B_c  = pB[(size_t)t * NBC];
      float C_c  = pB[(size_t)t * NBC + DS];
      float dA = __expf(dt_c * A);
      s = fmaf(dA, s, dt_c * x_c * B_c);
      P[j] = s * C_c;
    }
#pragma unroll
    for (int j = 0; j < 16; ++j) Pb[wid][j][lane] = P[j];
    int t4 = lane >> 2, q = lane & 3;
    const float* row = &Pb[wid][t4][q * 16];
    float part = 0.f;
#pragma unroll
    for (int k = 0; k < 8; ++k) {
      float2 v2 = *(const float2*)(row + 2 * k);
      part += v2.x + v2.y;
    }
    part = bp_add(part, (lane ^ 1) << 2);
    part = bp_add(part, (lane ^ 2) << 2);
    float got = __int_as_float(
        __builtin_amdgcn_ds_bpermute((lane & 15) << 4, __float_as_int(part)));
    yv = ((lane >> 4) == sb) ? got : yv;
  }
  float sig = 1.f / (1.f + __expf(-zv));
  y[(size_t)(l0 + lane) * DI + d] = f2bf((yv + xv * Dd) * (zv * sig));
}

// ---------------------------------------------------------------------------
// out_proj + residual: out = x + y . Wo^T  (grid 24 x 16)
// ---------------------------------------------------------------------------
__global__ __launch_bounds__(256) void k_outproj(const short* __restrict__ y,
                                                 const short* __restrict__ wo,
                                                 const float* __restrict__ x,
                                                 float* __restrict__ out) {
  __shared__ float4v red[16 * 64];
  int lane = threadIdx.x & 63, w = threadIdx.x >> 6;
  int row, col;
  float4v v = gemm32_core(y, DI, wo, DI, DI, blockIdx.x, blockIdx.y,
                          lane, w, red, &row, &col);
#pragma unroll
  for (int r = 0; r < 4; ++r)
    out[(size_t)(row + r) * DM + col] = v[r] + x[(size_t)(row + r) * DM + col];
}

// ---------------------------------------------------------------------------
// Launcher (7 dispatches)
// ---------------------------------------------------------------------------
extern "C" void kernel_launch(void* const* d_in, const int* in_sizes, int n_in,
                              void* d_out, int out_size, void* d_ws, size_t ws_size,
                              hipStream_t stream) {
  const float* x         = (const float*)d_in[0];
  const float* ln_w      = (const float*)d_in[1];
  const float* ln_b      = (const float*)d_in[2];
  const float* in_proj_w = (const float*)d_in[3];
  const float* conv_w    = (const float*)d_in[4];
  const float* conv_b    = (const float*)d_in[5];
  const float* x_proj_w  = (const float*)d_in[6];
  const float* dt_proj_w = (const float*)d_in[7];
  const float* dt_proj_b = (const float*)d_in[8];
  const float* A_log     = (const float*)d_in[9];
  const float* Dv        = (const float*)d_in[10];
  const float* out_proj_w= (const float*)d_in[11];
  float* out = (float*)d_out;

  float* ws = (float*)d_ws;
  // f32 region
  float* xz     = ws;                      // 1572864
  float* xconv  = xz + 1572864;            // 786432
  float* xdblBC = xconv + 786432;          // 512*128 = 65536
  float* dtb    = xdblBC + 65536;          // 786432
  float* send   = dtb + 786432;            // 7*1536*64 = 688128
  float* dts    = send + 688128;           // 10752
  float* fend   = dts + 10752;
  // bf16 region
  short* h_bf   = (short*)fend;            // 393216
  short* wi_bf  = h_bf + 393216;           // 2359296
  short* wo_bf  = wi_bf + 2359296;         // 1179648
  short* wcomb  = wo_bf + 1179648;         // 1664*1536 = 2555904
  short* xc_bf  = wcomb + 2555904;         // 786432
  short* y_bf   = xc_bf + 786432;          // 786432

  // 1. prep: LN + weight cvts + Weff (Wdt.Wx_dt) fused-weight build
  prep<<<PREP_GRID, 256, 0, stream>>>(x, ln_w, ln_b, h_bf, in_proj_w, wi_bf,
                                      x_proj_w, dt_proj_w, wcomb,
                                      out_proj_w, wo_bf);

  // 2. in_proj: xz = h . Wi^T
  k_inproj<<<dim3(2 * DI / 32, L_SEQ / 32), 256, 0, stream>>>(h_bf, wi_bf, xz);

  // 3. conv + SiLU
  conv_silu_kernel<<<(L_SEQ * DI) / 256, 256, 0, stream>>>(xz, conv_w, conv_b,
                                                           xconv, xc_bf);

  // 4. proj2: [B/C | dt] = xconv . Wcomb^T (x_proj + dt_proj fused)
  k_proj2<<<dim3(NP2 / 32, L_SEQ / 32), 256, 0, stream>>>(
      xc_bf, wcomb, xdblBC, dtb, dt_proj_b);

  // 5-6. chunked selective scan (p2 folded into p3's inline prefix)
  scan_p1<<<((NC - 1) * DI) / 4, 256, 0, stream>>>(dtb, xconv, xdblBC, A_log,
                                                   send, dts);
  scan_p3<<<(NC * DI) / 4, 256, 0, stream>>>(dtb, xconv, xdblBC, A_log, Dv, xz,
                                             send, dts, y_bf);

  // 7. out_proj + residual
  k_outproj<<<dim3(DM / 32, L_SEQ / 32), 256, 0, stream>>>(y_bf, wo_bf, x, out);
}

// Round 10
// 187.566 us; speedup vs baseline: 3.7211x; 1.0928x over previous
//
#include <hip/hip_runtime.h>
#include <hip/hip_bf16.h>
#include <math.h>

#define L_SEQ 512
#define DM 768
#define DI 1536
#define DS 64
#define DC 4
#define DR 48
#define NBC 128          // B/C output columns (2*DS)
#define NP2 (NBC + DI)   // 1664: proj2 output width (B/C | dt)
#define NC 8             // time chunks
#define TC 64            // steps per chunk

typedef __attribute__((ext_vector_type(8))) short short8;
typedef __attribute__((ext_vector_type(4))) float float4v;

// prep job partition (1024-elem cvt jobs + LN rows + Weff tiles)
#define J_LN 512
#define J_WI (2 * DI * DM / 1024)   // 2304
#define J_WBC (NBC * DI / 1024)     // 192
#define J_WO (DM * DI / 1024)       // 1152
#define J_WEFF ((DI / 64) * (DI / 64))  // 576
#define PREP_GRID (J_LN + J_WI + J_WBC + J_WO + J_WEFF)  // 4736

// ---------------------------------------------------------------------------
// helpers
// ---------------------------------------------------------------------------
__device__ __forceinline__ float bp_add(float p, int addr) {
  return p + __int_as_float(__builtin_amdgcn_ds_bpermute(addr, __float_as_int(p)));
}
__device__ __forceinline__ float lane_read(float v, int t) {
  return __int_as_float(__builtin_amdgcn_readlane(__float_as_int(v), t));
}
__device__ __forceinline__ short f2bf(float v) {
  __hip_bfloat16 h = __float2bfloat16(v);
  return *reinterpret_cast<short*>(&h);
}
__device__ __forceinline__ short8 cvt8f(const float* p, bool valid) {
  float4 u = *(const float4*)(p);
  float4 v = *(const float4*)(p + 4);
  short8 r;
  r[0] = f2bf(u.x); r[1] = f2bf(u.y); r[2] = f2bf(u.z); r[3] = f2bf(u.w);
  r[4] = f2bf(v.x); r[5] = f2bf(v.y); r[6] = f2bf(v.z); r[7] = f2bf(v.w);
  if (!valid) r = (short8)0;
  return r;
}
__device__ __forceinline__ void cvt_blk(const float* __restrict__ s,
                                        short* __restrict__ d, int b) {
  int i = b * 1024 + threadIdx.x * 4;
  float4 v = *(const float4*)(s + i);
  short4 o; o.x = f2bf(v.x); o.y = f2bf(v.y); o.z = f2bf(v.z); o.w = f2bf(v.w);
  *(short4*)(d + i) = o;
}

// ---------------------------------------------------------------------------
// 32x32-tile GEMM core with 4-wave intra-block K-split + LDS reduce
// (verified R9). Returns quadrant accumulator; caller computes coords:
// lrow=(w&1)*16+(lane>>4)*4, lcol=(w>>1)*16+(lane&15).
// ---------------------------------------------------------------------------
__device__ __forceinline__ float4v gemm32_core(
    const short* __restrict__ A, int lda, const short* __restrict__ B, int ldb,
    int K, int bx, int by, int lane, int w, float4v* red) {
  int ks = K >> 2;
  int kbeg = w * ks;
  int fr = lane & 15, koff = (lane >> 4) * 8;
  int m0 = by * 32, n0 = bx * 32;
  const short* pA0 = A + (size_t)(m0 + fr) * lda + koff + kbeg;
  const short* pA1 = pA0 + (size_t)16 * lda;
  const short* pB0 = B + (size_t)(n0 + fr) * ldb + koff + kbeg;
  const short* pB1 = pB0 + (size_t)16 * ldb;
  float4v acc00 = (float4v){0.f,0.f,0.f,0.f}, acc01 = acc00;
  float4v acc10 = acc00, acc11 = acc00;
  short8 a0A = *(const short8*)(pA0);      short8 a1A = *(const short8*)(pA1);
  short8 b0A = *(const short8*)(pB0);      short8 b1A = *(const short8*)(pB1);
  short8 a0B = *(const short8*)(pA0 + 32); short8 a1B = *(const short8*)(pA1 + 32);
  short8 b0B = *(const short8*)(pB0 + 32); short8 b1B = *(const short8*)(pB1 + 32);
  for (int k0 = 0; k0 < ks; k0 += 64) {
    short8 ca0 = a0A, ca1 = a1A, cb0 = b0A, cb1 = b1A;
    short8 da0 = a0B, da1 = a1B, db0 = b0B, db1 = b1B;
    int nA = k0 + 64; if (nA >= ks) nA = 0;
    int nB = k0 + 96; if (nB >= ks) nB = 32;
    a0A = *(const short8*)(pA0 + nA); a1A = *(const short8*)(pA1 + nA);
    b0A = *(const short8*)(pB0 + nA); b1A = *(const short8*)(pB1 + nA);
    a0B = *(const short8*)(pA0 + nB); a1B = *(const short8*)(pA1 + nB);
    b0B = *(const short8*)(pB0 + nB); b1B = *(const short8*)(pB1 + nB);
    acc00 = __builtin_amdgcn_mfma_f32_16x16x32_bf16(ca0, cb0, acc00, 0, 0, 0);
    acc01 = __builtin_amdgcn_mfma_f32_16x16x32_bf16(ca0, cb1, acc01, 0, 0, 0);
    acc10 = __builtin_amdgcn_mfma_f32_16x16x32_bf16(ca1, cb0, acc10, 0, 0, 0);
    acc11 = __builtin_amdgcn_mfma_f32_16x16x32_bf16(ca1, cb1, acc11, 0, 0, 0);
    acc00 = __builtin_amdgcn_mfma_f32_16x16x32_bf16(da0, db0, acc00, 0, 0, 0);
    acc01 = __builtin_amdgcn_mfma_f32_16x16x32_bf16(da0, db1, acc01, 0, 0, 0);
    acc10 = __builtin_amdgcn_mfma_f32_16x16x32_bf16(da1, db0, acc10, 0, 0, 0);
    acc11 = __builtin_amdgcn_mfma_f32_16x16x32_bf16(da1, db1, acc11, 0, 0, 0);
  }
  red[(w * 4 + 0) * 64 + lane] = acc00;
  red[(w * 4 + 1) * 64 + lane] = acc01;
  red[(w * 4 + 2) * 64 + lane] = acc10;
  red[(w * 4 + 3) * 64 + lane] = acc11;
  __syncthreads();
  float4v v = red[(0 * 4 + w) * 64 + lane];
  v = v + red[(1 * 4 + w) * 64 + lane];
  v = v + red[(2 * 4 + w) * 64 + lane];
  v = v + red[(3 * 4 + w) * 64 + lane];
  return v;
}

// ---------------------------------------------------------------------------
// 32x32 transposed store: block's C-tile -> dst[n_local][m0 + m_local],
// row stride ldT. Reuses `t` (>= 32*33 floats; the red buffer).
// ---------------------------------------------------------------------------
__device__ __forceinline__ void trans_store32(float* t, float4v v,
                                              int lrow, int lcol, int tid,
                                              float* dst, size_t ldT, int m0) {
  __syncthreads();   // all waves done reading red
#pragma unroll
  for (int r = 0; r < 4; ++r) t[lcol * 33 + lrow + r] = v[r];
  __syncthreads();
  int i = tid >> 3, j = (tid & 7) * 4;
  float4 o = make_float4(t[i * 33 + j], t[i * 33 + j + 1],
                         t[i * 33 + j + 2], t[i * 33 + j + 3]);
  *(float4*)&dst[(size_t)i * ldT + m0 + j] = o;
}

// ---------------------------------------------------------------------------
// prep: LN + cvt(Wi) + cvt(Wx B/C rows -> Wcomb[0..127]) + cvt(Wo)
//       + Weff tiles (Wcomb[128..1663] = Wdt . Wx_dt, K=48 pad 64). (R9)
// ---------------------------------------------------------------------------
__global__ __launch_bounds__(256) void prep(
    const float* __restrict__ x, const float* __restrict__ lnw,
    const float* __restrict__ lnb, short* __restrict__ h,
    const float* __restrict__ wi, short* __restrict__ wib,
    const float* __restrict__ wx, const float* __restrict__ wdt,
    short* __restrict__ wcomb, const float* __restrict__ wo,
    short* __restrict__ wob) {
  __shared__ float ls[4], ls2[4];
  int b = blockIdx.x;
  int tid = threadIdx.x, lane = tid & 63, w = tid >> 6;
  if (b < J_LN) {
    int l = b;
    const float* xr = x + l * DM;
    float s = 0.f, s2 = 0.f;
    for (int i = tid; i < DM; i += 256) { float t = xr[i]; s += t; s2 += t * t; }
#pragma unroll
    for (int off = 32; off; off >>= 1) { s += __shfl_xor(s, off); s2 += __shfl_xor(s2, off); }
    if (lane == 0) { ls[w] = s; ls2[w] = s2; }
    __syncthreads();
    s = ls[0] + ls[1] + ls[2] + ls[3];
    s2 = ls2[0] + ls2[1] + ls2[2] + ls2[3];
    float mean = s * (1.f / DM);
    float var = s2 * (1.f / DM) - mean * mean;
    float rstd = rsqrtf(var + 1e-5f);
    for (int i = tid; i < DM; i += 256)
      h[l * DM + i] = f2bf((xr[i] - mean) * rstd * lnw[i] + lnb[i]);
    return;
  }
  b -= J_LN;
  if (b < J_WI) { cvt_blk(wi, wib, b); return; }
  b -= J_WI;
  if (b < J_WBC) { cvt_blk(wx + DR * DI, wcomb, b); return; }
  b -= J_WBC;
  if (b < J_WO) { cvt_blk(wo, wob, b); return; }
  b -= J_WO;
  {
    int tm = b / (DI / 64), tn = b % (DI / 64);
    int qi = w & 1, qj = w >> 1;
    int m0 = tm * 64 + qi * 32, n0 = tn * 64 + qj * 32;
    int fr = lane & 15, koff = (lane >> 4) * 8;
    const float* pA0 = wdt + (size_t)(m0 + fr) * DR;
    const float* pA1 = pA0 + (size_t)16 * DR;
    float4v a00 = (float4v){0.f,0.f,0.f,0.f}, a01 = a00, a10 = a00, a11 = a00;
#pragma unroll
    for (int k0 = 0; k0 < 64; k0 += 32) {
      bool valid = (k0 + koff) < DR;
      int off = valid ? k0 + koff : 0;
      short8 fa0 = cvt8f(pA0 + off, valid);
      short8 fa1 = cvt8f(pA1 + off, valid);
      short8 fb0, fb1;
#pragma unroll
      for (int j = 0; j < 8; ++j) {
        int r = k0 + koff + j;
        fb0[j] = valid ? f2bf(wx[(size_t)r * DI + n0 + fr]) : (short)0;
        fb1[j] = valid ? f2bf(wx[(size_t)r * DI + n0 + 16 + fr]) : (short)0;
      }
      a00 = __builtin_amdgcn_mfma_f32_16x16x32_bf16(fa0, fb0, a00, 0, 0, 0);
      a01 = __builtin_amdgcn_mfma_f32_16x16x32_bf16(fa0, fb1, a01, 0, 0, 0);
      a10 = __builtin_amdgcn_mfma_f32_16x16x32_bf16(fa1, fb0, a10, 0, 0, 0);
      a11 = __builtin_amdgcn_mfma_f32_16x16x32_bf16(fa1, fb1, a11, 0, 0, 0);
    }
    int rb = (lane >> 4) * 4, cb = lane & 15;
#pragma unroll
    for (int r = 0; r < 4; ++r) {
      wcomb[(size_t)(NBC + m0 + rb + r) * DI + n0 + cb]      = f2bf(a00[r]);
      wcomb[(size_t)(NBC + m0 + rb + r) * DI + n0 + 16 + cb] = f2bf(a01[r]);
      wcomb[(size_t)(NBC + m0 + 16 + rb + r) * DI + n0 + cb]      = f2bf(a10[r]);
      wcomb[(size_t)(NBC + m0 + 16 + rb + r) * DI + n0 + 16 + cb] = f2bf(a11[r]);
    }
  }
}

// ---------------------------------------------------------------------------
// in_proj: cols<DI -> xz_in[l][col] (f32, conv input);
//          cols>=DI -> zt[d][l] transposed (coalesced tile store).
// grid 96 x 16
// ---------------------------------------------------------------------------
__global__ __launch_bounds__(256) void k_inproj(const short* __restrict__ h,
                                                const short* __restrict__ wi,
                                                float* __restrict__ xz_in,
                                                float* __restrict__ zt) {
  __shared__ float4v red[16 * 64];
  int tid = threadIdx.x, lane = tid & 63, w = tid >> 6;
  float4v v = gemm32_core(h, DM, wi, DM, DM, blockIdx.x, blockIdx.y, lane, w, red);
  int lrow = ((w & 1) << 4) + ((lane >> 4) << 2);
  int lcol = ((w >> 1) << 4) + (lane & 15);
  int m0 = blockIdx.y * 32, n0 = blockIdx.x * 32;
  if (n0 < DI) {
#pragma unroll
    for (int r = 0; r < 4; ++r)
      xz_in[(size_t)(m0 + lrow + r) * DI + n0 + lcol] = v[r];
  } else {
    trans_store32((float*)red, v, lrow, lcol, tid,
                  zt + (size_t)(n0 - DI) * L_SEQ, L_SEQ, m0);
  }
}

// ---------------------------------------------------------------------------
// conv + SiLU: tile 64d x 32l; thread = (d, 8-l run). Outputs
// xc_bf[l][d] (bf16 for proj2) and xct[d][l] (f32 for scan, LDS-transposed).
// grid 24 x 16
// ---------------------------------------------------------------------------
__global__ __launch_bounds__(256) void conv_silu_kernel(const float* __restrict__ xz_in,
                                                        const float* __restrict__ cw,
                                                        const float* __restrict__ cb,
                                                        short* __restrict__ xc_bf,
                                                        float* __restrict__ xct) {
  __shared__ float t2[64 * 34];
  int tid = threadIdx.x;
  int dloc = tid & 63, lseg = tid >> 6;
  int d0 = blockIdx.x * 64, l0 = blockIdx.y * 32;
  int d = d0 + dloc;
  int lb = l0 + lseg * 8;
  float xin[11];
#pragma unroll
  for (int i = 0; i < 11; ++i) {
    int l = lb - 3 + i;
    xin[i] = (l >= 0) ? xz_in[(size_t)l * DI + d] : 0.f;
  }
  float w0 = cw[d * 4 + 0], w1 = cw[d * 4 + 1];
  float w2 = cw[d * 4 + 2], w3 = cw[d * 4 + 3];
  float bias = cb[d];
#pragma unroll
  for (int j = 0; j < 8; ++j) {
    float acc = bias;
    acc = fmaf(w0, xin[j], acc);
    acc = fmaf(w1, xin[j + 1], acc);
    acc = fmaf(w2, xin[j + 2], acc);
    acc = fmaf(w3, xin[j + 3], acc);
    float sig = 1.f / (1.f + __expf(-acc));
    float v = acc * sig;
    xc_bf[(size_t)(lb + j) * DI + d] = f2bf(v);
    t2[dloc * 34 + lseg * 8 + j] = v;
  }
  __syncthreads();
  int row = tid >> 2, j4 = (tid & 3) * 8;
  const float* src = &t2[row * 34 + j4];
  float2 o0 = *(const float2*)(src + 0);
  float2 o1 = *(const float2*)(src + 2);
  float2 o2 = *(const float2*)(src + 4);
  float2 o3 = *(const float2*)(src + 6);
  float* dst = &xct[(size_t)(d0 + row) * L_SEQ + l0 + j4];
  *(float2*)(dst + 0) = o0; *(float2*)(dst + 2) = o1;
  *(float2*)(dst + 4) = o2; *(float2*)(dst + 6) = o3;
}

// ---------------------------------------------------------------------------
// proj2: cols<128 -> xdblBC[l][n] (B/C, row-major for scan's coalesced reads);
//        cols>=128 -> softplus(+bias) -> dtt[d][l] transposed tile store.
// grid 52 x 16
// ---------------------------------------------------------------------------
__global__ __launch_bounds__(256) void k_proj2(const short* __restrict__ xc,
                                               const short* __restrict__ wcomb,
                                               float* __restrict__ xdblBC,
                                               float* __restrict__ dtt,
                                               const float* __restrict__ bias) {
  __shared__ float4v red[16 * 64];
  int tid = threadIdx.x, lane = tid & 63, w = tid >> 6;
  float4v v = gemm32_core(xc, DI, wcomb, DI, DI, blockIdx.x, blockIdx.y,
                          lane, w, red);
  int lrow = ((w & 1) << 4) + ((lane >> 4) << 2);
  int lcol = ((w >> 1) << 4) + (lane & 15);
  int m0 = blockIdx.y * 32, n0 = blockIdx.x * 32;
  if (n0 < NBC) {
#pragma unroll
    for (int r = 0; r < 4; ++r)
      xdblBC[(size_t)(m0 + lrow + r) * NBC + n0 + lcol] = v[r];
  } else {
    float bi = bias[n0 - NBC + lcol];
#pragma unroll
    for (int r = 0; r < 4; ++r) {
      float t = v[r] + bi;
      v[r] = (t > 20.f) ? t : log1pf(__expf(t));
    }
    trans_store32((float*)red, v, lrow, lcol, tid,
                  dtt + (size_t)(n0 - NBC) * L_SEQ, L_SEQ, m0);
  }
}

// ---------------------------------------------------------------------------
// Scan pass 1 (chunks 0..NC-2): coalesced dtt/xct preloads.
// ---------------------------------------------------------------------------
__global__ __launch_bounds__(256) void scan_p1(const float* __restrict__ dtt,
                                               const float* __restrict__ xct,
                                               const float* __restrict__ xdblBC,
                                               const float* __restrict__ A_log,
                                               float* __restrict__ send,
                                               float* __restrict__ dts) {
  int lane = threadIdx.x & 63;
  int wid = threadIdx.x >> 6;
  int pair = blockIdx.x * 4 + wid;
  int c = __builtin_amdgcn_readfirstlane(pair / DI);
  int d = __builtin_amdgcn_readfirstlane(pair - (pair / DI) * DI);
  float A = -__expf(A_log[(size_t)d * DS + lane]);
  int l0 = c * TC;
  float dtv = dtt[(size_t)d * L_SEQ + l0 + lane];
  float xv  = xct[(size_t)d * L_SEQ + l0 + lane];
  const float* pB = xdblBC + (size_t)l0 * NBC + lane;
  float s = 0.f;
#pragma unroll 8
  for (int t = 0; t < TC; ++t) {
    float dt_c = lane_read(dtv, t);
    float x_c  = lane_read(xv, t);
    float B_c  = pB[(size_t)t * NBC];
    float dA = __expf(dt_c * A);
    s = fmaf(dA, s, dt_c * x_c * B_c);
  }
  float dsum = dtv;
  dsum = bp_add(dsum, (lane ^ 1) << 2);  dsum = bp_add(dsum, (lane ^ 2) << 2);
  dsum = bp_add(dsum, (lane ^ 4) << 2);  dsum = bp_add(dsum, (lane ^ 8) << 2);
  dsum = bp_add(dsum, (lane ^ 16) << 2); dsum = bp_add(dsum, (lane ^ 32) << 2);
  send[((size_t)c * DI + d) * DS + lane] = s;
  if (lane == 0) dts[c * DI + d] = dsum;
}

// ---------------------------------------------------------------------------
// Scan pass 3: inline chunk-prefix; coalesced preloads; LDS-batched
// n-reduction; y stored via LDS short4 rows (block = 4 consecutive d).
// ---------------------------------------------------------------------------
__global__ __launch_bounds__(256) void scan_p3(const float* __restrict__ dtt,
                                               const float* __restrict__ xct,
                                               const float* __restrict__ xdblBC,
                                               const float* __restrict__ A_log,
                                               const float* __restrict__ Dv,
                                               const float* __restrict__ zt,
                                               const float* __restrict__ send,
                                               const float* __restrict__ dts,
                                               short* __restrict__ y) {
  __shared__ float Pb[4][16][66];
  __shared__ float ys[64][5];
  int tid = threadIdx.x;
  int lane = tid & 63;
  int wid = tid >> 6;
  int pair = blockIdx.x * 4 + wid;
  int c = __builtin_amdgcn_readfirstlane(pair / DI);
  int d = __builtin_amdgcn_readfirstlane(pair - (pair / DI) * DI);
  float A = -__expf(A_log[(size_t)d * DS + lane]);
  float Dd = Dv[d];
  int l0 = c * TC;
  float dtv = dtt[(size_t)d * L_SEQ + l0 + lane];
  float xv  = xct[(size_t)d * L_SEQ + l0 + lane];
  float zv  = zt[(size_t)d * L_SEQ + l0 + lane];
  float s = 0.f;
  for (int cc = 0; cc < c; ++cc) {
    float P = __expf(A * dts[cc * DI + d]);
    s = fmaf(P, s, send[((size_t)cc * DI + d) * DS + lane]);
  }
  const float* pB = xdblBC + (size_t)l0 * NBC + lane;
  float yv = 0.f;
#pragma unroll
  for (int sb = 0; sb < 4; ++sb) {
    float P[16];
#pragma unroll
    for (int j = 0; j < 16; ++j) {
      int t = sb * 16 + j;
      float dt_c = lane_read(dtv, t);
      float x_c  = lane_read(xv, t);
      float B_c  = pB[(size_t)t * NBC];
      float C_c  = pB[(size_t)t * NBC + DS];
      float dA = __expf(dt_c * A);
      s = fmaf(dA, s, dt_c * x_c * B_c);
      P[j] = s * C_c;
    }
#pragma unroll
    for (int j = 0; j < 16; ++j) Pb[wid][j][lane] = P[j];
    int t4 = lane >> 2, q = lane & 3;
    const float* row = &Pb[wid][t4][q * 16];
    float part = 0.f;
#pragma unroll
    for (int k = 0; k < 8; ++k) {
      float2 v2 = *(const float2*)(row + 2 * k);
      part += v2.x + v2.y;
    }
    part = bp_add(part, (lane ^ 1) << 2);
    part = bp_add(part, (lane ^ 2) << 2);
    float got = __int_as_float(
        __builtin_amdgcn_ds_bpermute((lane & 15) << 4, __float_as_int(part)));
    yv = ((lane >> 4) == sb) ? got : yv;
  }
  float sig = 1.f / (1.f + __expf(-zv));
  ys[lane][wid] = (yv + xv * Dd) * (zv * sig);
  __syncthreads();
  if (tid < 64) {
    int d0 = (blockIdx.x * 4) % DI;
    short4 o;
    o.x = f2bf(ys[tid][0]); o.y = f2bf(ys[tid][1]);
    o.z = f2bf(ys[tid][2]); o.w = f2bf(ys[tid][3]);
    *(short4*)&y[(size_t)(l0 + tid) * DI + d0] = o;
  }
}

// ---------------------------------------------------------------------------
// out_proj + residual: out = x + y . Wo^T  (grid 24 x 16)
// ---------------------------------------------------------------------------
__global__ __launch_bounds__(256) void k_outproj(const short* __restrict__ y,
                                                 const short* __restrict__ wo,
                                                 const float* __restrict__ x,
                                                 float* __restrict__ out) {
  __shared__ float4v red[16 * 64];
  int tid = threadIdx.x, lane = tid & 63, w = tid >> 6;
  float4v v = gemm32_core(y, DI, wo, DI, DI, blockIdx.x, blockIdx.y, lane, w, red);
  int lrow = ((w & 1) << 4) + ((lane >> 4) << 2);
  int lcol = ((w >> 1) << 4) + (lane & 15);
  int row = blockIdx.y * 32 + lrow, col = blockIdx.x * 32 + lcol;
#pragma unroll
  for (int r = 0; r < 4; ++r)
    out[(size_t)(row + r) * DM + col] = v[r] + x[(size_t)(row + r) * DM + col];
}

// ---------------------------------------------------------------------------
// Launcher (7 dispatches)
// ---------------------------------------------------------------------------
extern "C" void kernel_launch(void* const* d_in, const int* in_sizes, int n_in,
                              void* d_out, int out_size, void* d_ws, size_t ws_size,
                              hipStream_t stream) {
  const float* x         = (const float*)d_in[0];
  const float* ln_w      = (const float*)d_in[1];
  const float* ln_b      = (const float*)d_in[2];
  const float* in_proj_w = (const float*)d_in[3];
  const float* conv_w    = (const float*)d_in[4];
  const float* conv_b    = (const float*)d_in[5];
  const float* x_proj_w  = (const float*)d_in[6];
  const float* dt_proj_w = (const float*)d_in[7];
  const float* dt_proj_b = (const float*)d_in[8];
  const float* A_log     = (const float*)d_in[9];
  const float* Dv        = (const float*)d_in[10];
  const float* out_proj_w= (const float*)d_in[11];
  float* out = (float*)d_out;

  float* ws = (float*)d_ws;
  // f32 region
  float* xz_in  = ws;                      // 512*1536 = 786432
  float* zt     = xz_in + 786432;          // 1536*512 = 786432 (transposed z)
  float* xct    = zt + 786432;             // 1536*512 = 786432 (transposed conv)
  float* dtt    = xct + 786432;            // 1536*512 = 786432 (transposed dt)
  float* xdblBC = dtt + 786432;            // 512*128  = 65536
  float* send   = xdblBC + 65536;          // 7*1536*64 = 688128
  float* dts    = send + 688128;           // 10752
  float* fend   = dts + 10752;
  // bf16 region
  short* h_bf   = (short*)fend;            // 393216
  short* wi_bf  = h_bf + 393216;           // 2359296
  short* wo_bf  = wi_bf + 2359296;         // 1179648
  short* wcomb  = wo_bf + 1179648;         // 1664*1536 = 2555904
  short* xc_bf  = wcomb + 2555904;         // 786432
  short* y_bf   = xc_bf + 786432;          // 786432

  // 1. prep: LN + weight cvts + Weff build
  prep<<<PREP_GRID, 256, 0, stream>>>(x, ln_w, ln_b, h_bf, in_proj_w, wi_bf,
                                      x_proj_w, dt_proj_w, wcomb,
                                      out_proj_w, wo_bf);

  // 2. in_proj: x_in row-major + z transposed
  k_inproj<<<dim3(2 * DI / 32, L_SEQ / 32), 256, 0, stream>>>(h_bf, wi_bf,
                                                              xz_in, zt);

  // 3. conv + SiLU: bf16 row-major + f32 transposed
  conv_silu_kernel<<<dim3(DI / 64, L_SEQ / 32), 256, 0, stream>>>(
      xz_in, conv_w, conv_b, xc_bf, xct);

  // 4. proj2: [B/C | dt] = xconv . Wcomb^T (dt transposed + softplus)
  k_proj2<<<dim3(NP2 / 32, L_SEQ / 32), 256, 0, stream>>>(
      xc_bf, wcomb, xdblBC, dtt, dt_proj_b);

  // 5-6. chunked selective scan
  scan_p1<<<((NC - 1) * DI) / 4, 256, 0, stream>>>(dtt, xct, xdblBC, A_log,
                                                   send, dts);
  scan_p3<<<(NC * DI) / 4, 256, 0, stream>>>(dtt, xct, xdblBC, A_log, Dv, zt,
                                             send, dts, y_bf);

  // 7. out_proj + residual
  k_outproj<<<dim3(DM / 32, L_SEQ / 32), 256, 0, stream>>>(y_bf, wo_bf, x, out);
}